// Round 1
// baseline (1471.753 us; speedup 1.0000x reference)
//
#include <hip/hip_runtime.h>
#include <math.h>

#define NPER  4096
#define NBAT  4
#define NTOT  16384
#define EPER  49152
#define ETOT  196608
#define FD    128
#define F3    384
#define KR    20
#define PI_F  3.14159265358979f

__device__ __forceinline__ float silu_f(float x){ return x / (1.0f + __expf(-x)); }

// ---------------- edge precompute: send/recv, cut, dirn, edge_state, recv counts --------
__global__ __launch_bounds__(256) void edge_kernel(
    const float* __restrict__ xyz, const float* __restrict__ cell,
    const int* __restrict__ aedges, const float* __restrict__ edisp,
    int* __restrict__ sendb, int* __restrict__ recvb,
    float* __restrict__ cutb, float* __restrict__ dirnb,
    float* __restrict__ esb, int* __restrict__ counts)
{
    int e = blockIdx.x * blockDim.x + threadIdx.x;
    if (e >= ETOT) return;
    int b = e / EPER;
    int s = aedges[(size_t)e*2+0] + b*NPER;
    int r = aedges[(size_t)e*2+1] + b*NPER;
    const float* cb = cell + b*9;
    float c0 = edisp[(size_t)e*3+0], c1 = edisp[(size_t)e*3+1], c2 = edisp[(size_t)e*3+2];
    float diff[3];
    #pragma unroll
    for (int d=0; d<3; ++d) {
        float disp = c0*cb[d] + c1*cb[3+d] + c2*cb[6+d];
        diff[d] = xyz[(size_t)r*3+d] - (xyz[(size_t)s*3+d] + disp);
    }
    float dist = sqrtf(diff[0]*diff[0]+diff[1]*diff[1]+diff[2]*diff[2]);
    cutb[e] = (dist < 5.0f) ? 0.5f*(cosf(PI_F*dist*0.2f)+1.0f) : 0.0f;
    float invg = 1.0f/fmaxf(dist,1e-12f);
    #pragma unroll
    for (int d=0; d<3; ++d) dirnb[(size_t)e*3+d] = diff[d]*invg;
    float invd = 1.0f/dist;
    float ang = dist*(PI_F*0.2f);
    #pragma unroll
    for (int k=0;k<KR;++k) esb[(size_t)e*KR+k] = sinf(ang*(float)(k+1))*invd;
    sendb[e]=s; recvb[e]=r;
    atomicAdd(&counts[r],1);
}

// ---------------- exclusive scan of counts[NTOT] -> row_off[NTOT+1] (single block) ------
__global__ __launch_bounds__(1024) void scan_kernel(const int* __restrict__ counts,
                                                    int* __restrict__ row_off)
{
    __shared__ int sdata[1024];
    int t = threadIdx.x;
    int base = t * 16;
    int local[16];
    int s = 0;
    #pragma unroll
    for (int i=0;i<16;++i){ local[i]=s; s += counts[base+i]; }
    sdata[t] = s;
    __syncthreads();
    for (int off=1; off<1024; off<<=1) {
        int val = (t>=off) ? sdata[t-off] : 0;
        __syncthreads();
        sdata[t] += val;
        __syncthreads();
    }
    int chunk_off = (t==0) ? 0 : sdata[t-1];
    #pragma unroll
    for (int i=0;i<16;++i) row_off[base+i] = chunk_off + local[i];
    if (t==1023) row_off[NTOT] = sdata[1023];
}

// ---------------- CSR fill ----------------
__global__ __launch_bounds__(256) void fill_kernel(const int* __restrict__ recvb,
    const int* __restrict__ row_off, int* __restrict__ cursor, int* __restrict__ perm)
{
    int e = blockIdx.x * blockDim.x + threadIdx.x;
    if (e >= ETOT) return;
    int r = recvb[e];
    int slot = atomicAdd(&cursor[r], 1);
    perm[row_off[r] + slot] = e;
}

// ---------------- h = [atom_emb[nodes], V*potW + potb]  (NTOT x 256) ----------------
__global__ __launch_bounds__(256) void hbuild_kernel(const int* __restrict__ nodes,
    const float* __restrict__ atom_emb, const float* __restrict__ V_flat,
    const float* __restrict__ pot_W, const float* __restrict__ pot_b,
    float* __restrict__ h)
{
    int t = blockIdx.x * blockDim.x + threadIdx.x;   // NTOT*256
    int n = t >> 8, k = t & 255;
    float val;
    if (k < FD) val = atom_emb[(size_t)nodes[n]*FD + k];
    else { int f = k - FD; val = V_flat[n]*pot_W[f] + pot_b[f]; }
    h[t] = val;
}

// ---------------- v0 = E_flat[:,c] * vec_w[f] ----------------
__global__ __launch_bounds__(256) void v0_kernel(const float* __restrict__ E_flat,
    const float* __restrict__ vec_w, float* __restrict__ v0)
{
    int t = blockIdx.x * blockDim.x + threadIdx.x;   // NTOT*384
    int n = t / F3, r = t - n*F3;
    int c = r >> 7, f = r & 127;
    v0[t] = E_flat[(size_t)n*3 + c] * vec_w[f];
}

// ---------------- generic SGEMM: C[M x Nout] = act(A[M x K] @ W[Nout x K]^T + b) -------
// grid (Nout/64, M/64), 256 threads, 4x4 per thread, BK=16
template<int ACT>
__global__ __launch_bounds__(256) void gemm_kernel(
    const float* __restrict__ A, int lda,
    const float* __restrict__ W,
    const float* __restrict__ bias,
    float* __restrict__ C, int ldc, int Kdim)
{
    __shared__ float As[16][64];
    __shared__ float Ws[16][64];
    const int tid = threadIdx.x;
    const int tn = tid & 15, tm = tid >> 4;
    const int row0 = blockIdx.y * 64, col0 = blockIdx.x * 64;
    float acc[4][4] = {};
    const int r  = tid >> 2;
    const int kg = (tid & 3) << 2;
    const float* Aptr = A + (size_t)(row0 + r) * lda + kg;
    const float* Wptr = W + (size_t)(col0 + r) * Kdim + kg;
    for (int k0 = 0; k0 < Kdim; k0 += 16) {
        float4 av = *(const float4*)(Aptr + k0);
        float4 wv = *(const float4*)(Wptr + k0);
        __syncthreads();
        As[kg+0][r]=av.x; As[kg+1][r]=av.y; As[kg+2][r]=av.z; As[kg+3][r]=av.w;
        Ws[kg+0][r]=wv.x; Ws[kg+1][r]=wv.y; Ws[kg+2][r]=wv.z; Ws[kg+3][r]=wv.w;
        __syncthreads();
        #pragma unroll
        for (int k=0;k<16;++k){
            float4 a4 = *(const float4*)&As[k][tm<<2];
            float4 w4 = *(const float4*)&Ws[k][tn<<2];
            acc[0][0]+=a4.x*w4.x; acc[0][1]+=a4.x*w4.y; acc[0][2]+=a4.x*w4.z; acc[0][3]+=a4.x*w4.w;
            acc[1][0]+=a4.y*w4.x; acc[1][1]+=a4.y*w4.y; acc[1][2]+=a4.y*w4.z; acc[1][3]+=a4.y*w4.w;
            acc[2][0]+=a4.z*w4.x; acc[2][1]+=a4.z*w4.y; acc[2][2]+=a4.z*w4.z; acc[2][3]+=a4.z*w4.w;
            acc[3][0]+=a4.w*w4.x; acc[3][1]+=a4.w*w4.y; acc[3][2]+=a4.w*w4.z; acc[3][3]+=a4.w*w4.w;
        }
    }
    float4 bv = make_float4(0.f,0.f,0.f,0.f);
    if (bias) bv = *(const float4*)&bias[col0 + (tn<<2)];
    #pragma unroll
    for (int i=0;i<4;++i){
        int rr = row0 + (tm<<2) + i;
        float4 res;
        res.x = acc[i][0] + bv.x; res.y = acc[i][1] + bv.y;
        res.z = acc[i][2] + bv.z; res.w = acc[i][3] + bv.w;
        if (ACT) { res.x=silu_f(res.x); res.y=silu_f(res.y); res.z=silu_f(res.z); res.w=silu_f(res.w); }
        *(float4*)&C[(size_t)rr*ldc + col0 + (tn<<2)] = res;
    }
}

// ---------------- fused edge filter + gather aggregation (per recv node) ----------------
// 128 threads/block (thread = f), grid-stride over nodes.
__global__ __launch_bounds__(128) void agg_kernel(
    const float* __restrict__ s_prev, int s_lda,
    const float* __restrict__ v_prev, int v_nstr,
    const float* __restrict__ so,
    const float* __restrict__ esb, const float* __restrict__ cutb,
    const float* __restrict__ dirnb,
    const int* __restrict__ row_off, const int* __restrict__ perm,
    const int* __restrict__ sendb,
    const float* __restrict__ fW, const float* __restrict__ fb,
    float* __restrict__ s_mid, float* __restrict__ v_mid)
{
    __shared__ float fWs[F3][KR+1];   // pad 20 -> 21 to avoid bank conflicts
    __shared__ float fbs[F3];
    const int f = threadIdx.x;
    for (int i = f; i < F3*KR; i += 128) fWs[i/KR][i - (i/KR)*KR] = fW[i];
    for (int i = f; i < F3; i += 128) fbs[i] = fb[i];
    __syncthreads();

    for (int n = blockIdx.x; n < NTOT; n += gridDim.x) {
        int beg = row_off[n], end = row_off[n+1];
        float acc_s = 0.f, acc_v0 = 0.f, acc_v1 = 0.f, acc_v2 = 0.f;
        for (int idx = beg; idx < end; ++idx) {
            int e  = perm[idx];
            int sd = sendb[e];
            float ct = cutb[e];
            float esv[KR];
            #pragma unroll
            for (int k=0;k<KR;++k) esv[k] = esb[(size_t)e*KR + k];
            float g_sv = fbs[f], g_ev = fbs[FD+f], g_ns = fbs[2*FD+f];
            #pragma unroll
            for (int k=0;k<KR;++k) {
                g_sv += esv[k]*fWs[f][k];
                g_ev += esv[k]*fWs[FD+f][k];
                g_ns += esv[k]*fWs[2*FD+f][k];
            }
            const float* sop = so + (size_t)sd*F3;
            float fo_sv = g_sv*ct * sop[f];
            float fo_ev = g_ev*ct * sop[FD+f];
            float fo_ns = g_ns*ct * sop[2*FD+f];
            acc_s += s_prev[(size_t)sd*s_lda + f] * fo_ns;
            float d0 = dirnb[(size_t)e*3+0], d1 = dirnb[(size_t)e*3+1], d2 = dirnb[(size_t)e*3+2];
            const float* vp = v_prev + (size_t)sd*v_nstr;
            acc_v0 += vp[f]      * fo_sv + fo_ev * d0;
            acc_v1 += vp[FD+f]   * fo_sv + fo_ev * d1;
            acc_v2 += vp[2*FD+f] * fo_sv + fo_ev * d2;
        }
        s_mid[(size_t)n*FD + f] = s_prev[(size_t)n*s_lda + f] + acc_s;
        const float* vpn = v_prev + (size_t)n*v_nstr;
        v_mid[((size_t)n*3+0)*FD + f] = vpn[f]      + acc_v0;
        v_mid[((size_t)n*3+1)*FD + f] = vpn[FD+f]   + acc_v1;
        v_mid[((size_t)n*3+2)*FD + f] = vpn[2*FD+f] + acc_v2;
    }
}

// ---------------- Vn, dot(Uv,Vv); builds m = [s_mid, Vn] ----------------
__global__ __launch_bounds__(256) void vndot_kernel(
    const float* __restrict__ Uv, const float* __restrict__ Vv,
    const float* __restrict__ s_mid,
    float* __restrict__ mbuf, float* __restrict__ dotb)
{
    int t = blockIdx.x * blockDim.x + threadIdx.x;   // NTOT*128
    int n = t >> 7, f = t & 127;
    size_t b0 = (size_t)n*3*FD + f;
    float u0 = Uv[b0], u1 = Uv[b0+FD], u2 = Uv[b0+2*FD];
    float w0 = Vv[b0], w1 = Vv[b0+FD], w2 = Vv[b0+2*FD];
    float vn  = sqrtf(w0*w0 + w1*w1 + w2*w2);
    dotb[t] = u0*w0 + u1*w1 + u2*w2;
    mbuf[(size_t)n*256 + f]      = s_mid[t];
    mbuf[(size_t)n*256 + FD + f] = vn;
}

// ---------------- epilogue: final residual updates, write out slice ----------------
__global__ __launch_bounds__(256) void epi_kernel(
    const float* __restrict__ s_mid, const float* __restrict__ v_mid,
    const float* __restrict__ a, const float* __restrict__ dotb,
    const float* __restrict__ Uv, float* __restrict__ outp)
{
    int t = blockIdx.x * blockDim.x + threadIdx.x;   // NTOT*128
    int n = t >> 7, f = t & 127;
    float a_ss = a[(size_t)n*F3 + f];
    float a_sv = a[(size_t)n*F3 + FD + f];
    float a_vv = a[(size_t)n*F3 + 2*FD + f];
    outp[(size_t)n*512 + f] = s_mid[t] + a_ss + a_sv*dotb[t];
    #pragma unroll
    for (int c=0;c<3;++c) {
        size_t vi = ((size_t)n*3 + c)*FD + f;
        outp[(size_t)n*512 + (1+c)*FD + f] = v_mid[vi] + a_vv*Uv[vi];
    }
}

extern "C" void kernel_launch(void* const* d_in, const int* in_sizes, int n_in,
                              void* d_out, int out_size, void* d_ws, size_t ws_size,
                              hipStream_t stream)
{
    (void)in_sizes; (void)n_in; (void)out_size; (void)ws_size;
    const float* atom_xyz = (const float*)d_in[0];
    const float* cell     = (const float*)d_in[1];
    const int*   nodes    = (const int*)d_in[2];
    const int*   aedges   = (const int*)d_in[3];
    const float* edisp    = (const float*)d_in[4];
    const float* V_flat   = (const float*)d_in[5];
    const float* E_flat   = (const float*)d_in[6];
    const float* atom_emb = (const float*)d_in[7];
    const float* pot_W    = (const float*)d_in[8];
    const float* pot_b    = (const float*)d_in[9];
    const float* init_W1  = (const float*)d_in[10];
    const float* init_b1  = (const float*)d_in[11];
    const float* init_W2  = (const float*)d_in[12];
    const float* init_b2  = (const float*)d_in[13];
    const float* vec_w    = (const float*)d_in[14];
    const float* filt_W   = (const float*)d_in[15];
    const float* filt_b   = (const float*)d_in[16];
    const float* msg_W1   = (const float*)d_in[17];
    const float* msg_b1   = (const float*)d_in[18];
    const float* msg_W2   = (const float*)d_in[19];
    const float* msg_b2   = (const float*)d_in[20];
    const float* U_W      = (const float*)d_in[21];
    const float* V_W      = (const float*)d_in[22];
    const float* upd_W1   = (const float*)d_in[23];
    const float* upd_b1   = (const float*)d_in[24];
    const float* upd_W2   = (const float*)d_in[25];
    const float* upd_b2   = (const float*)d_in[26];

    float* out = (float*)d_out;
    float* wsf = (float*)d_ws;
    size_t o = 0;
    auto alloc = [&](size_t nfl){ size_t r = o; o += (nfl + 63) & ~(size_t)63; return r; };
    float* s0    = wsf + alloc((size_t)NTOT*FD);
    float* v0    = wsf + alloc((size_t)NTOT*3*FD);
    float* s_mid = wsf + alloc((size_t)NTOT*FD);
    float* v_mid = wsf + alloc((size_t)NTOT*3*FD);
    float* hid   = wsf + alloc((size_t)NTOT*FD);
    float* so    = wsf + alloc((size_t)NTOT*F3);   // also h (Nx256) and 'a' (Nx384)
    float* Uv    = wsf + alloc((size_t)NTOT*3*FD);
    float* Vv    = wsf + alloc((size_t)NTOT*3*FD);
    float* mbuf  = wsf + alloc((size_t)NTOT*256);
    float* dotb  = wsf + alloc((size_t)NTOT*FD);
    float* esb   = wsf + alloc((size_t)ETOT*KR);
    float* cutb  = wsf + alloc((size_t)ETOT);
    float* dirnb = wsf + alloc((size_t)ETOT*3);
    int* sendb   = (int*)(wsf + alloc(ETOT));
    int* recvb   = (int*)(wsf + alloc(ETOT));
    int* row_off = (int*)(wsf + alloc(NTOT+1));
    int* counts  = (int*)(wsf + alloc(NTOT));
    int* cursor  = (int*)(wsf + alloc(NTOT));
    int* perm    = (int*)(wsf + alloc(ETOT));

    hipMemsetAsync(counts, 0, NTOT*sizeof(int), stream);
    hipMemsetAsync(cursor, 0, NTOT*sizeof(int), stream);

    edge_kernel<<<ETOT/256, 256, 0, stream>>>(atom_xyz, cell, aedges, edisp,
        sendb, recvb, cutb, dirnb, esb, counts);
    scan_kernel<<<1, 1024, 0, stream>>>(counts, row_off);
    fill_kernel<<<ETOT/256, 256, 0, stream>>>(recvb, row_off, cursor, perm);

    // init: h -> hid -> s0 ; v0
    hbuild_kernel<<<NTOT*256/256, 256, 0, stream>>>(nodes, atom_emb, V_flat, pot_W, pot_b, so);
    gemm_kernel<1><<<dim3(FD/64, NTOT/64), 256, 0, stream>>>(so, 256, init_W1, init_b1, hid, FD, 256);
    gemm_kernel<0><<<dim3(FD/64, NTOT/64), 256, 0, stream>>>(hid, FD, init_W2, init_b2, s0, FD, FD);
    v0_kernel<<<NTOT*F3/256, 256, 0, stream>>>(E_flat, vec_w, v0);

    const float* s_prev = s0;  int s_lda  = FD;
    const float* v_prev = v0;  int v_nstr = 3*FD;
    for (int l = 0; l < 3; ++l) {
        // message MLP: hid = silu(s_prev @ msg_W1^T + b1); so = hid @ msg_W2^T + b2
        gemm_kernel<1><<<dim3(FD/64, NTOT/64), 256, 0, stream>>>(
            s_prev, s_lda, msg_W1 + (size_t)l*FD*FD, msg_b1 + (size_t)l*FD, hid, FD, FD);
        gemm_kernel<0><<<dim3(F3/64, NTOT/64), 256, 0, stream>>>(
            hid, FD, msg_W2 + (size_t)l*F3*FD, msg_b2 + (size_t)l*F3, so, F3, FD);
        // aggregation (fused filter GEMM + gather)
        agg_kernel<<<2048, 128, 0, stream>>>(s_prev, s_lda, v_prev, v_nstr, so,
            esb, cutb, dirnb, row_off, perm, sendb,
            filt_W + (size_t)l*F3*KR, filt_b + (size_t)l*F3, s_mid, v_mid);
        // Uv, Vv  (M = 3N)
        gemm_kernel<0><<<dim3(FD/64, 3*NTOT/64), 256, 0, stream>>>(
            v_mid, FD, U_W + (size_t)l*FD*FD, (const float*)nullptr, Uv, FD, FD);
        gemm_kernel<0><<<dim3(FD/64, 3*NTOT/64), 256, 0, stream>>>(
            v_mid, FD, V_W + (size_t)l*FD*FD, (const float*)nullptr, Vv, FD, FD);
        // Vn, dot, build m
        vndot_kernel<<<NTOT*FD/256, 256, 0, stream>>>(Uv, Vv, s_mid, mbuf, dotb);
        // update MLP: hid = silu(m @ upd_W1^T + b1); a(so) = hid @ upd_W2^T + b2
        gemm_kernel<1><<<dim3(FD/64, NTOT/64), 256, 0, stream>>>(
            mbuf, 256, upd_W1 + (size_t)l*FD*256, upd_b1 + (size_t)l*FD, hid, FD, 256);
        gemm_kernel<0><<<dim3(F3/64, NTOT/64), 256, 0, stream>>>(
            hid, FD, upd_W2 + (size_t)l*F3*FD, upd_b2 + (size_t)l*F3, so, F3, FD);
        // epilogue -> out slice l
        float* outp = out + (size_t)l*NTOT*512;
        epi_kernel<<<NTOT*FD/256, 256, 0, stream>>>(s_mid, v_mid, so, dotb, Uv, outp);
        s_prev = outp;        s_lda  = 512;
        v_prev = outp + FD;   v_nstr = 512;
    }
}